// Round 10
// baseline (184.473 us; speedup 1.0000x reference)
//
#include <hip/hip_runtime.h>

// Problem constants (reference: clip_embeddings [32, 1024, 512] fp32)
#define BB 32
#define NN 1024
#define DD 512
#define KK 512            // k = N * 0.5
#define EPSF 1e-8f

#define CPB1 8            // k1 blocks per batch (writes 8 partials/batch)
#define TPB1 128          // tokens per k1 block
#define CPB2 32           // k2 blocks per batch
#define TPB2 32           // tokens per k2 block
#define TPW 8             // tokens per load group (both)

__device__ __forceinline__ float wsumf(float v) {
#pragma unroll
    for (int m = 1; m < 64; m <<= 1) v += __shfl_xor(v, m, 64);
    return v;
}
__device__ __forceinline__ int wsumi(int v) {
#pragma unroll
    for (int m = 1; m < 64; m <<= 1) v += __shfl_xor(v, m, 64);
    return v;
}

// K1: norms + per-block unit-vector partial sums. grid = BB*CPB1 = 256 blocks
// (1/CU), 256 threads (4 waves). Each wave owns 32 consecutive tokens,
// processed in 4 groups of 8 (16 float4 in flight -> MLP). Only HBM-cold pass
// over x (64 MB). Writes just 8 partial vectors per batch (cuts k2's
// redundant re-read from 64 MB to 16 MB vs R7).
__global__ __launch_bounds__(256, 4) void k1_norms_partials(const float* __restrict__ x,
                                                            float* __restrict__ norms,
                                                            float* __restrict__ partials) {
    int blk = blockIdx.x;
    int b = blk / CPB1, c = blk % CPB1;
    int tid = threadIdx.x, wave = tid >> 6, lane = tid & 63;
    int tok0 = c * TPB1 + wave * 32;
    const float* base = x + (size_t)(b * NN + tok0) * DD;

    float4 a0 = {0, 0, 0, 0}, a1 = {0, 0, 0, 0};
#pragma unroll
    for (int g = 0; g < 4; ++g) {
        float4 xs0[TPW], xs1[TPW];
#pragma unroll
        for (int t = 0; t < TPW; ++t) {
            const float4* p = reinterpret_cast<const float4*>(
                base + (size_t)(g * TPW + t) * DD) + lane * 2;
            xs0[t] = p[0];
            xs1[t] = p[1];
        }
#pragma unroll
        for (int t = 0; t < TPW; ++t) {
            float4 v0 = xs0[t], v1 = xs1[t];
            float ssq = v0.x * v0.x + v0.y * v0.y + v0.z * v0.z + v0.w * v0.w +
                        v1.x * v1.x + v1.y * v1.y + v1.z * v1.z + v1.w * v1.w;
            ssq = wsumf(ssq);
            float nrm = sqrtf(ssq);
            if (lane == 0) norms[b * NN + tok0 + g * TPW + t] = nrm;
            float inv = 1.0f / fmaxf(nrm, EPSF);
            a0.x += v0.x * inv; a0.y += v0.y * inv; a0.z += v0.z * inv; a0.w += v0.w * inv;
            a1.x += v1.x * inv; a1.y += v1.y * inv; a1.z += v1.z * inv; a1.w += v1.w * inv;
        }
    }

    __shared__ float red[4][DD];
    {
        float4* rr = reinterpret_cast<float4*>(&red[wave][lane * 8]);
        rr[0] = a0; rr[1] = a1;
    }
    __syncthreads();
#pragma unroll
    for (int i = 0; i < 2; ++i) {
        int d = tid + i * 256;
        partials[(size_t)blk * DD + d] = red[0][d] + red[1][d] + red[2][d] + red[3][d];
    }
}

// K2: per-block reduce of the batch's 8 partials -> sum_unit (LDS, fixed
// order, deterministic), then scores for this block's 32 tokens.
// grid = BB*CPB2 = 1024 blocks (4/CU), 256 threads. c==0 blocks zero out[b]
// (stream order guarantees completion before k34's atomics).
__global__ __launch_bounds__(256, 4) void k2_scores(const float* __restrict__ x,
                                                    const float* __restrict__ norms,
                                                    const float* __restrict__ partials,
                                                    float* __restrict__ scores,
                                                    float* __restrict__ out) {
    int blk = blockIdx.x;
    int b = blk / CPB2, c = blk % CPB2;
    int tid = threadIdx.x, wave = tid >> 6, lane = tid & 63;

    __shared__ __align__(16) float su_lds[DD];
    {
        float s0 = 0.f, s1 = 0.f;
        const float* pb = partials + (size_t)b * CPB1 * DD;
#pragma unroll
        for (int cc = 0; cc < CPB1; ++cc) {       // fixed order: deterministic
            s0 += pb[(size_t)cc * DD + tid];
            s1 += pb[(size_t)cc * DD + tid + 256];
        }
        su_lds[tid] = s0;
        su_lds[tid + 256] = s1;
    }
    if (c == 0) {                                  // zero out[b] for k34
        out[b * DD + tid] = 0.f;
        out[b * DD + tid + 256] = 0.f;
    }
    __syncthreads();

    float4 su0 = reinterpret_cast<const float4*>(&su_lds[lane * 8])[0];
    float4 su1 = reinterpret_cast<const float4*>(&su_lds[lane * 8])[1];

    int tok0 = c * TPB2 + wave * TPW;
    const float* base = x + (size_t)(b * NN + tok0) * DD;
#pragma unroll
    for (int t = 0; t < TPW; ++t) {
        const float4* p = reinterpret_cast<const float4*>(base + (size_t)t * DD) + lane * 2;
        float4 v0 = p[0], v1 = p[1];
        float d = v0.x * su0.x + v0.y * su0.y + v0.z * su0.z + v0.w * su0.w +
                  v1.x * su1.x + v1.y * su1.y + v1.z * su1.z + v1.w * su1.w;
        d = wsumf(d);
        if (lane == 0) {
            float nrm = norms[b * NN + tok0 + t];
            scores[b * NN + tok0 + t] = d / (fmaxf(nrm, EPSF) * (float)NN);
        }
    }
}

// K34: fused rank-count selection + gather (proven in R7). grid = BB*8
// blocks (8/batch -> 256 blocks), 256 threads (4 waves, 32 tokens/wave).
// Rank-count reproduces lax.top_k's stable tie-break (greater, or equal with
// lower index); wave-parallel count via float4 LDS reads + wsumi. Selected
// tokens accumulate; block reduce; 8 atomicAdds/element (out zeroed by k2).
__global__ __launch_bounds__(256, 4) void k34_select_gather(const float* __restrict__ x,
                                                            const float* __restrict__ scores,
                                                            float* __restrict__ out) {
    int blk = blockIdx.x;
    int b = blk >> 3, g = blk & 7;
    int tid = threadIdx.x, wave = tid >> 6, lane = tid & 63;

    __shared__ __align__(16) float s_lds[NN];
    reinterpret_cast<float4*>(s_lds)[tid] =
        reinterpret_cast<const float4*>(scores + b * NN)[tid];   // 256*4 = 1024
    __syncthreads();

    const float4* sv = reinterpret_cast<const float4*>(s_lds);
    float4 c0 = {0, 0, 0, 0}, c1 = {0, 0, 0, 0};
    int tok0 = g * 128 + wave * 32;

#pragma unroll 4
    for (int t = 0; t < 32; ++t) {
        int n = tok0 + t;
        float my = s_lds[n];                      // broadcast: free
        int cnt = 0;
#pragma unroll
        for (int i = 0; i < 4; ++i) {
            int j4 = i * 64 + lane;               // conflict-free b128 reads
            float4 v = sv[j4];
            int j = j4 * 4;
            cnt += (v.x > my) || (v.x == my && (j + 0) < n);
            cnt += (v.y > my) || (v.y == my && (j + 1) < n);
            cnt += (v.z > my) || (v.z == my && (j + 2) < n);
            cnt += (v.w > my) || (v.w == my && (j + 3) < n);
        }
        cnt = wsumi(cnt);                         // wave-uniform rank
        if (cnt < KK) {                           // wave-uniform branch
            const float4* p = reinterpret_cast<const float4*>(
                x + (size_t)(b * NN + n) * DD) + lane * 2;
            float4 v0 = p[0], v1 = p[1];
            c0.x += v0.x; c0.y += v0.y; c0.z += v0.z; c0.w += v0.w;
            c1.x += v1.x; c1.y += v1.y; c1.z += v1.z; c1.w += v1.w;
        }
    }

    __shared__ float red[4][DD];
    {
        float4* rr = reinterpret_cast<float4*>(&red[wave][lane * 8]);
        rr[0] = c0; rr[1] = c1;
    }
    __syncthreads();
#pragma unroll
    for (int i = 0; i < 2; ++i) {
        int d = tid + i * 256;
        float v = red[0][d] + red[1][d] + red[2][d] + red[3][d];
        atomicAdd(&out[b * DD + d], v * (1.0f / (float)KK));   // 8 adds/addr
    }
}

extern "C" void kernel_launch(void* const* d_in, const int* in_sizes, int n_in,
                              void* d_out, int out_size, void* d_ws, size_t ws_size,
                              hipStream_t stream) {
    const float* x = (const float*)d_in[0];
    float* out = (float*)d_out;

    float* ws = (float*)d_ws;
    float* partials = ws;                               // 256*512 = 512 KB
    float* scores   = ws + BB * CPB1 * DD;              // BB*NN = 128 KB
    float* norms    = ws + BB * CPB1 * DD + BB * NN;    // BB*NN = 128 KB

    k1_norms_partials<<<dim3(BB * CPB1), dim3(256), 0, stream>>>(x, norms, partials);
    k2_scores<<<dim3(BB * CPB2), dim3(256), 0, stream>>>(x, norms, partials, scores, out);
    k34_select_gather<<<dim3(BB * 8), dim3(256), 0, stream>>>(x, scores, out);
}

// Round 11
// 116.598 us; speedup vs baseline: 1.5821x; 1.5821x over previous
//
#include <hip/hip_runtime.h>

// Problem constants (reference: clip_embeddings [32, 1024, 512] fp32)
#define BB 32
#define NN 1024
#define DD 512
#define KK 512            // k = N * 0.5
#define EPSF 1e-8f

#define CPB 32            // chunks (blocks) per batch for k1/k2
#define TPB 32            // tokens per block  (k1/k2)
#define TPW 8             // tokens per wave   (k1/k2)

__device__ __forceinline__ float wsumf(float v) {
#pragma unroll
    for (int m = 1; m < 64; m <<= 1) v += __shfl_xor(v, m, 64);
    return v;
}
__device__ __forceinline__ int wsumi(int v) {
#pragma unroll
    for (int m = 1; m < 64; m <<= 1) v += __shfl_xor(v, m, 64);
    return v;
}

// K1 (R7-proven, byte-for-byte): norms + per-block unit-vector partial sums.
// grid = BB*CPB = 1024 blocks (4/CU), 256 threads (4 waves). Each wave owns
// 8 tokens; all 16 float4 loads issue up front (MLP, no spill: fits the
// (256,4) VGPR budget). Only HBM-cold pass over x (64 MB).
__global__ __launch_bounds__(256, 4) void k1_norms_partials(const float* __restrict__ x,
                                                            float* __restrict__ norms,
                                                            float* __restrict__ partials) {
    int blk = blockIdx.x;
    int b = blk / CPB, c = blk % CPB;
    int tid = threadIdx.x, wave = tid >> 6, lane = tid & 63;
    int tok0 = c * TPB + wave * TPW;
    const float* base = x + (size_t)(b * NN + tok0) * DD;

    float4 xs0[TPW], xs1[TPW];
#pragma unroll
    for (int t = 0; t < TPW; ++t) {
        const float4* p = reinterpret_cast<const float4*>(base + (size_t)t * DD) + lane * 2;
        xs0[t] = p[0];
        xs1[t] = p[1];
    }

    float4 a0 = {0, 0, 0, 0}, a1 = {0, 0, 0, 0};
#pragma unroll
    for (int t = 0; t < TPW; ++t) {
        float4 v0 = xs0[t], v1 = xs1[t];
        float ssq = v0.x * v0.x + v0.y * v0.y + v0.z * v0.z + v0.w * v0.w +
                    v1.x * v1.x + v1.y * v1.y + v1.z * v1.z + v1.w * v1.w;
        ssq = wsumf(ssq);
        float nrm = sqrtf(ssq);
        if (lane == 0) norms[b * NN + tok0 + t] = nrm;
        float inv = 1.0f / fmaxf(nrm, EPSF);
        a0.x += v0.x * inv; a0.y += v0.y * inv; a0.z += v0.z * inv; a0.w += v0.w * inv;
        a1.x += v1.x * inv; a1.y += v1.y * inv; a1.z += v1.z * inv; a1.w += v1.w * inv;
    }

    __shared__ float red[4][DD];
    {
        float4* rr = reinterpret_cast<float4*>(&red[wave][lane * 8]);
        rr[0] = a0; rr[1] = a1;
    }
    __syncthreads();
#pragma unroll
    for (int i = 0; i < 2; ++i) {
        int d = tid + i * 256;
        partials[(size_t)blk * DD + d] = red[0][d] + red[1][d] + red[2][d] + red[3][d];
    }
}

// K2 (R7-proven, byte-for-byte): per-block reduce of the batch's 32 partials
// -> sum_unit (LDS, fixed order = deterministic; the 32x redundancy is
// L2-broadcast, ~2 us total), then scores for this block's 32 tokens.
// c==0 blocks zero out[b] (stream order precedes k34's atomics).
__global__ __launch_bounds__(256, 4) void k2_scores(const float* __restrict__ x,
                                                    const float* __restrict__ norms,
                                                    const float* __restrict__ partials,
                                                    float* __restrict__ scores,
                                                    float* __restrict__ out) {
    int blk = blockIdx.x;
    int b = blk / CPB, c = blk % CPB;
    int tid = threadIdx.x, wave = tid >> 6, lane = tid & 63;

    __shared__ __align__(16) float su_lds[DD];
    {
        float s0 = 0.f, s1 = 0.f;
        const float* pb = partials + (size_t)b * CPB * DD;
#pragma unroll
        for (int cc = 0; cc < CPB; ++cc) {          // fixed order: deterministic
            s0 += pb[(size_t)cc * DD + tid];
            s1 += pb[(size_t)cc * DD + tid + 256];
        }
        su_lds[tid] = s0;
        su_lds[tid + 256] = s1;
    }
    if (c == 0) {                                    // zero out[b] for k34
        out[b * DD + tid] = 0.f;
        out[b * DD + tid + 256] = 0.f;
    }
    __syncthreads();

    float4 su0 = reinterpret_cast<const float4*>(&su_lds[lane * 8])[0];
    float4 su1 = reinterpret_cast<const float4*>(&su_lds[lane * 8])[1];

    int tok0 = c * TPB + wave * TPW;
    const float* base = x + (size_t)(b * NN + tok0) * DD;
#pragma unroll
    for (int t = 0; t < TPW; ++t) {
        const float4* p = reinterpret_cast<const float4*>(base + (size_t)t * DD) + lane * 2;
        float4 v0 = p[0], v1 = p[1];
        float d = v0.x * su0.x + v0.y * su0.y + v0.z * su0.z + v0.w * su0.w +
                  v1.x * su1.x + v1.y * su1.y + v1.z * su1.z + v1.w * su1.w;
        d = wsumf(d);
        if (lane == 0) {
            float nrm = norms[b * NN + tok0 + t];
            scores[b * NN + tok0 + t] = d / (fmaxf(nrm, EPSF) * (float)NN);
        }
    }
}

// K34 (R11 change: 256 -> 1024 blocks for occupancy; inner loops unchanged).
// grid = BB*32 blocks (32/batch), 256 threads (4 waves, 8 tokens/wave ->
// 32 tokens/block). R7 ran this at 1 block/CU = 4 waves/CU and was
// latency-bound on the 32 MB gather (R9 lesson); now 4 blocks/CU = 16
// waves/CU like k1/k2. Rank-count reproduces lax.top_k's stable tie-break
// (greater, or equal with lower index); wave-parallel count via float4 LDS
// reads + wsumi. Block reduce; 32 atomicAdds/element (out zeroed by k2).
__global__ __launch_bounds__(256, 4) void k34_select_gather(const float* __restrict__ x,
                                                            const float* __restrict__ scores,
                                                            float* __restrict__ out) {
    int blk = blockIdx.x;
    int b = blk >> 5, g = blk & 31;
    int tid = threadIdx.x, wave = tid >> 6, lane = tid & 63;

    __shared__ __align__(16) float s_lds[NN];
    reinterpret_cast<float4*>(s_lds)[tid] =
        reinterpret_cast<const float4*>(scores + b * NN)[tid];   // 256*4 = 1024
    __syncthreads();

    const float4* sv = reinterpret_cast<const float4*>(s_lds);
    float4 c0 = {0, 0, 0, 0}, c1 = {0, 0, 0, 0};
    int tok0 = g * 32 + wave * TPW;

#pragma unroll
    for (int t = 0; t < TPW; ++t) {
        int n = tok0 + t;
        float my = s_lds[n];                      // broadcast: free
        int cnt = 0;
#pragma unroll
        for (int i = 0; i < 4; ++i) {
            int j4 = i * 64 + lane;               // conflict-free b128 reads
            float4 v = sv[j4];
            int j = j4 * 4;
            cnt += (v.x > my) || (v.x == my && (j + 0) < n);
            cnt += (v.y > my) || (v.y == my && (j + 1) < n);
            cnt += (v.z > my) || (v.z == my && (j + 2) < n);
            cnt += (v.w > my) || (v.w == my && (j + 3) < n);
        }
        cnt = wsumi(cnt);                         // wave-uniform rank
        if (cnt < KK) {                           // wave-uniform branch
            const float4* p = reinterpret_cast<const float4*>(
                x + (size_t)(b * NN + n) * DD) + lane * 2;
            float4 v0 = p[0], v1 = p[1];
            c0.x += v0.x; c0.y += v0.y; c0.z += v0.z; c0.w += v0.w;
            c1.x += v1.x; c1.y += v1.y; c1.z += v1.z; c1.w += v1.w;
        }
    }

    __shared__ float red[4][DD];
    {
        float4* rr = reinterpret_cast<float4*>(&red[wave][lane * 8]);
        rr[0] = c0; rr[1] = c1;
    }
    __syncthreads();
#pragma unroll
    for (int i = 0; i < 2; ++i) {
        int d = tid + i * 256;
        float v = red[0][d] + red[1][d] + red[2][d] + red[3][d];
        atomicAdd(&out[b * DD + d], v * (1.0f / (float)KK));   // 32 adds/addr
    }
}

extern "C" void kernel_launch(void* const* d_in, const int* in_sizes, int n_in,
                              void* d_out, int out_size, void* d_ws, size_t ws_size,
                              hipStream_t stream) {
    const float* x = (const float*)d_in[0];
    float* out = (float*)d_out;

    float* ws = (float*)d_ws;
    float* partials = ws;                               // 1024*512 = 2 MB
    float* scores   = ws + BB * CPB * DD;               // BB*NN = 128 KB
    float* norms    = ws + BB * CPB * DD + BB * NN;     // BB*NN = 128 KB

    k1_norms_partials<<<dim3(BB * CPB), dim3(256), 0, stream>>>(x, norms, partials);
    k2_scores<<<dim3(BB * CPB), dim3(256), 0, stream>>>(x, norms, partials, scores, out);
    k34_select_gather<<<dim3(BB * 32), dim3(256), 0, stream>>>(x, scores, out);
}